// Round 5
// baseline (468.642 us; speedup 1.0000x reference)
//
#include <hip/hip_runtime.h>

#define N_  16
#define T_  1024
#define D_  2000
#define K_  21
#define P_  10
#define NT_ (N_*T_)   // 16384

// ---------------- K0: pad W rows [D][21] -> [D][24] (aligned rows) --------
__global__ void k_padW(const float* __restrict__ W0, const float* __restrict__ W1,
                       float* __restrict__ W0p, float* __restrict__ W1p) {
    int gid = blockIdx.x * blockDim.x + threadIdx.x;
    if (gid >= D_ * 24) return;
    int d = gid / 24, kk = gid - d * 24;
    W0p[gid] = (kk < K_) ? W0[d * K_ + kk] : 0.f;
    W1p[gid] = (kk < K_) ? W1[d * K_ + kk] : 0.f;
}

// ---------------- K1: coefficient GEMM ------------------------------------
// grid 1024 = 256 row-groups x 4 d-quarters (512 wide, padded to 2048).
// Coalesced float4 global->LDS staging, double-buffered 64x33 tiles.
// lane = row; d-loop wave-uniform -> scalar W row loads. Quarter h=1
// straddles the d=1000 group boundary -> uniform branch selects accM/accP.
__global__ __launch_bounds__(256)
void k_coef(const float* __restrict__ x,
            const float* __restrict__ W0p, const float* __restrict__ W1p,
            float* __restrict__ q0, float* __restrict__ q1,
            float* __restrict__ q2, float* __restrict__ q3,
            float* __restrict__ m0, float* __restrict__ m1,
            float* __restrict__ p1, float* __restrict__ p2,
            float* __restrict__ p3) {
    __shared__ float lds[5888];            // 23.5 KB: xs overlay (4224) / red (5888)
    const int tid  = threadIdx.x;
    const int lane = tid & 63;
    const int w    = __builtin_amdgcn_readfirstlane(tid >> 6);
    const int rg   = blockIdx.x >> 2;
    const int h    = blockIdx.x & 3;
    const int r0   = rg * 64;
    const int d0q  = h * 512;

    float a0[K_], am[K_], ap[K_];
#pragma unroll
    for (int k = 0; k < K_; ++k) { a0[k] = 0.f; am[k] = 0.f; ap[k] = 0.f; }

    const int srow = tid >> 2;             // 0..63
    const int sc4  = (tid & 3) * 2;        // f4 index 0,2,4,6 (loads sc4, sc4+1)
    float4 ra, rb;

    auto load_tile = [&](int dt) {
        const int d = d0q + dt + sc4 * 4;
        const float* p = x + (size_t)(r0 + srow) * D_ + d;
        ra = (d     < D_) ? *reinterpret_cast<const float4*>(p)
                          : make_float4(0.f, 0.f, 0.f, 0.f);
        rb = (d + 4 < D_) ? *reinterpret_cast<const float4*>(p + 4)
                          : make_float4(0.f, 0.f, 0.f, 0.f);
    };
    auto write_tile = [&](int buf) {
        float* b = lds + buf * 2112 + srow * 33 + sc4 * 4;
        b[0] = ra.x; b[1] = ra.y; b[2] = ra.z; b[3] = ra.w;
        b[4] = rb.x; b[5] = rb.y; b[6] = rb.z; b[7] = rb.w;
    };

    load_tile(0);
    write_tile(0);
    __syncthreads();

    for (int t = 0; t < 16; ++t) {
        if (t < 15) load_tile((t + 1) * 32);
        const float* xrow = lds + (t & 1) * 2112 + lane * 33;
#pragma unroll
        for (int c = 0; c < 8; ++c) {
            const int col = w * 8 + c;
            const int d = d0q + t * 32 + col;              // wave-uniform
            const int du = (d < D_) ? d : (D_ - 1);        // clamp (xv==0 there)
            const float xv = xrow[col];
            const float* __restrict__ wr0 = W0p + du * 24;
            const float* __restrict__ wr1 = W1p + du * 24;
#pragma unroll
            for (int k = 0; k < K_; ++k) a0[k] = fmaf(xv, wr0[k], a0[k]);
            if (d < 1000) {
#pragma unroll
                for (int k = 0; k < K_; ++k) am[k] = fmaf(xv, wr1[k], am[k]);
            } else {
#pragma unroll
                for (int k = 0; k < K_; ++k) ap[k] = fmaf(xv, wr1[k], ap[k]);
            }
        }
        if (t < 15) write_tile((t + 1) & 1);
        __syncthreads();
    }

    // cross-wave reduce (stride 23 -> 2-way banks) + store, per destination
    auto reduce_store = [&](const float* acc, float* dst) {
        __syncthreads();
#pragma unroll
        for (int k = 0; k < K_; ++k) lds[tid * 23 + k] = acc[k];
        __syncthreads();
        for (int o = tid; o < 64 * K_; o += 256) {
            int t = o / K_, j = o - t * K_;
            float s = lds[t * 23 + j] + lds[(64 + t) * 23 + j] +
                      lds[(128 + t) * 23 + j] + lds[(192 + t) * 23 + j];
            dst[(size_t)(r0 + t) * K_ + j] = s;
        }
    };

    float* const qd[4] = {q0, q1, q2, q3};
    reduce_store(a0, qd[h]);
    if (h == 0) reduce_store(am, m0);
    if (h == 1) { reduce_store(am, m1); reduce_store(ap, p1); }
    if (h == 2) reduce_store(ap, p2);
    if (h == 3) reduce_store(ap, p3);
}

// ---------------- K1.5: finalize w0, compute w1 (LDS-staged) ---------------
// w0 = q0+q1+q2+q3 ; M = m0+m1 ; P = p1+p2+p3
// w1[row,k] = P[row,k] + sum_j w0[row,j] * M[row+j-10, k]
__global__ __launch_bounds__(256)
void k_finish(const float* __restrict__ q0, const float* __restrict__ q1,
              const float* __restrict__ q2, const float* __restrict__ q3,
              const float* __restrict__ m0, const float* __restrict__ m1,
              const float* __restrict__ p1, const float* __restrict__ p2,
              const float* __restrict__ p3,
              float* __restrict__ w0f, float* __restrict__ w1f) {
    __shared__ float w0s[64 * K_];      // own rows
    __shared__ float Ms[84 * K_];       // halo rows r0-10 .. r0+73
    const int tid = threadIdx.x;
    const int r0 = blockIdx.x * 64;

    for (int o = tid; o < 64 * K_; o += 256) {
        size_t g = (size_t)r0 * K_ + o;
        w0s[o] = q0[g] + q1[g] + q2[g] + q3[g];
    }
    for (int o = tid; o < 84 * K_; o += 256) {
        int i = o / K_, j = o - i * K_;
        int rr = r0 - P_ + i;
        float v = 0.f;
        if (rr >= 0 && rr < NT_) {
            size_t g = (size_t)rr * K_ + j;
            v = m0[g] + m1[g];
        }
        Ms[o] = v;
    }
    __syncthreads();

    for (int o = tid; o < 64 * K_; o += 256) {
        int row = o / K_, k = o - row * K_;
        size_t g = (size_t)(r0 + row) * K_ + k;
        float acc = p1[g] + p2[g] + p3[g];
        int t = (r0 + row) & (T_ - 1);
#pragma unroll
        for (int j = 0; j < K_; ++j) {
            int tt = t + j - P_;
            if (tt >= 0 && tt < T_)
                acc = fmaf(w0s[row * K_ + j], Ms[(row + j) * K_ + k], acc);
        }
        w1f[g] = acc;
        w0f[g] = w0s[o];
    }
}

// ---------------- K2/K3 fused: shift-conv over one channel group -----------
__global__ __launch_bounds__(256)
void k_conv(const float* __restrict__ x, const float* __restrict__ w0,
            const float* __restrict__ w1, float* __restrict__ out) {
    __shared__ float xsl[84][128];     // 43 KB
    __shared__ float wc[64 * K_];      // 5.4 KB
    const int b = blockIdx.x;
    const int grp = b >> 11;
    const float* __restrict__ coef = grp ? w1 : w0;
    const int dbase = grp * 1000;
    const int bb = b & 2047;
    const int dseg = bb & 7;
    const int tch = (bb >> 3) & 15;
    const int nn = bb >> 7;
    const int t0 = tch * 64;
    const int tid = threadIdx.x;
    const float* xb = x + (size_t)nn * T_ * D_;

    {
        const int scol = tid & 31, srow0 = tid >> 5;
#pragma unroll
        for (int pass = 0; pass < 11; ++pass) {
            int rr = srow0 + pass * 8;
            if (rr < 84) {
                int u = t0 - P_ + rr;
                int dl = dseg * 128 + scol * 4;
                float4 v = make_float4(0.f, 0.f, 0.f, 0.f);
                if (u >= 0 && u < T_ && dl < 1000)
                    v = *reinterpret_cast<const float4*>(xb + (size_t)u * D_ + dbase + dl);
                *reinterpret_cast<float4*>(&xsl[rr][scol * 4]) = v;
            }
        }
    }
    for (int o = tid; o < 64 * K_; o += 256) {
        int tl = o / K_, k = o - tl * K_;
        wc[o] = coef[((size_t)nn * T_ + t0 + tl) * K_ + k];
    }
    __syncthreads();

    const int col = tid & 31;
    const int tsub = tid >> 5;
    const int tl0 = tsub * 8;
    float4 acc[8];
#pragma unroll
    for (int g = 0; g < 8; ++g) acc[g] = make_float4(0.f, 0.f, 0.f, 0.f);

#pragma unroll
    for (int ul = 0; ul < 28; ++ul) {
        const int rr = tl0 + ul;
        const float4 xf = *reinterpret_cast<const float4*>(&xsl[rr][col * 4]);
#pragma unroll
        for (int g = 0; g < 8; ++g) {
            const int k = ul - g;
            if (k >= 0 && k < K_) {
                const float c = wc[(tl0 + g) * K_ + k];
                acc[g].x = fmaf(c, xf.x, acc[g].x);
                acc[g].y = fmaf(c, xf.y, acc[g].y);
                acc[g].z = fmaf(c, xf.z, acc[g].z);
                acc[g].w = fmaf(c, xf.w, acc[g].w);
            }
        }
    }

    const int dl = dseg * 128 + col * 4;
    if (dl < 1000) {
#pragma unroll
        for (int g = 0; g < 8; ++g) {
            float* dst = out + ((size_t)nn * T_ + t0 + tl0 + g) * D_ + dbase + dl;
            *reinterpret_cast<float4*>(dst) = acc[g];
        }
    }
}

extern "C" void kernel_launch(void* const* d_in, const int* in_sizes, int n_in,
                              void* d_out, int out_size, void* d_ws, size_t ws_size,
                              hipStream_t stream) {
    const float* x  = (const float*)d_in[0];
    const float* W0 = (const float*)d_in[1];
    const float* W1 = (const float*)d_in[2];
    float* out = (float*)d_out;
    float* ws  = (float*)d_ws;

    const size_t CW = 344064;               // 16384*21
    float* W0p = ws;                        // 48000
    float* W1p = ws + 48000;                // 48000
    float* q0  = ws + 96000 + 0 * CW;
    float* q1  = ws + 96000 + 1 * CW;
    float* q2  = ws + 96000 + 2 * CW;
    float* q3  = ws + 96000 + 3 * CW;
    float* m0  = ws + 96000 + 4 * CW;
    float* m1  = ws + 96000 + 5 * CW;
    float* p1  = ws + 96000 + 6 * CW;
    float* p2  = ws + 96000 + 7 * CW;
    float* p3  = ws + 96000 + 8 * CW;
    float* w0f = ws + 96000 + 9 * CW;
    float* w1f = ws + 96000 + 10 * CW;      // total ~15.5 MB

    hipLaunchKernelGGL(k_padW, dim3(188), dim3(256), 0, stream, W0, W1, W0p, W1p);
    hipLaunchKernelGGL(k_coef, dim3(1024), dim3(256), 0, stream,
                       x, W0p, W1p, q0, q1, q2, q3, m0, m1, p1, p2, p3);
    hipLaunchKernelGGL(k_finish, dim3(256), dim3(256), 0, stream,
                       q0, q1, q2, q3, m0, m1, p1, p2, p3, w0f, w1f);
    hipLaunchKernelGGL(k_conv, dim3(4096), dim3(256), 0, stream, x, w0f, w1f, out);
}

// Round 7
// 438.519 us; speedup vs baseline: 1.0687x; 1.0687x over previous
//
#include <hip/hip_runtime.h>

#define N_  16
#define T_  1024
#define D_  2000
#define K_  21
#define P_  10
#define NT_ (N_*T_)   // 16384

// ---------------- K0: pad W rows [D][21] -> [D][24] (aligned rows) --------
__global__ void k_padW(const float* __restrict__ W0, const float* __restrict__ W1,
                       float* __restrict__ W0p, float* __restrict__ W1p) {
    int gid = blockIdx.x * blockDim.x + threadIdx.x;
    if (gid >= D_ * 24) return;
    int d = gid / 24, kk = gid - d * 24;
    W0p[gid] = (kk < K_) ? W0[d * K_ + kk] : 0.f;
    W1p[gid] = (kk < K_) ? W1[d * K_ + kk] : 0.f;
}

// ---------------- K1: coefficient GEMM ------------------------------------
// grid 1024 = 256 row-groups x 4 d-quarters (500 wide -> no group straddle).
// Coalesced float4 global->LDS staging (double-buffered 64x33 transpose).
// lane = row; d-loop wave-uniform. W rows loaded as per-lane VECTOR float4
// loads (opaque v_mov forces VGPR index) -> vmcnt-pipelined, broadcast in L1.
// h<2 accumulates M-partials (d<1000), h>=2 P-partials (d>=1000).
__global__ __launch_bounds__(256, 3)
void k_coef(const float* __restrict__ x,
            const float* __restrict__ W0p, const float* __restrict__ W1p,
            float* __restrict__ q0, float* __restrict__ q1,
            float* __restrict__ q2, float* __restrict__ q3,
            float* __restrict__ mp0, float* __restrict__ mp1,
            float* __restrict__ mp2, float* __restrict__ mp3) {
    __shared__ float lds[5888];            // 23.5 KB: 2x2112 xs / 5888 reduce
    const int tid  = threadIdx.x;
    const int lane = tid & 63;
    const int w    = __builtin_amdgcn_readfirstlane(tid >> 6);
    const int rg   = blockIdx.x >> 2;
    const int h    = blockIdx.x & 3;
    const int r0   = rg * 64;
    const int d0q  = h * 500;

    float a0[K_], a1[K_];
#pragma unroll
    for (int k = 0; k < K_; ++k) { a0[k] = 0.f; a1[k] = 0.f; }

    const int srow = tid >> 2;             // 0..63
    const int sf4  = (tid & 3) * 2;        // f4 slots sf4, sf4+1
    float4 ra, rb;

    auto load_tile = [&](int dt) {         // dt: tile base col in quarter
        const int c0 = dt + sf4 * 4;       // 500 % 4 == 0: f4 never straddles
        const float* p = x + (size_t)(r0 + srow) * D_ + d0q + c0;
        ra = (c0 < 500)     ? *reinterpret_cast<const float4*>(p)
                            : make_float4(0.f, 0.f, 0.f, 0.f);
        rb = (c0 + 4 < 500) ? *reinterpret_cast<const float4*>(p + 4)
                            : make_float4(0.f, 0.f, 0.f, 0.f);
    };
    auto write_tile = [&](int buf) {
        float* b = lds + buf * 2112 + srow * 33 + sf4 * 4;
        b[0] = ra.x; b[1] = ra.y; b[2] = ra.z; b[3] = ra.w;
        b[4] = rb.x; b[5] = rb.y; b[6] = rb.z; b[7] = rb.w;
    };

    load_tile(0);
    write_tile(0);
    __syncthreads();

    for (int t = 0; t < 16; ++t) {         // 15 full 32-tiles + 20-wide tail
        if (t < 15) load_tile((t + 1) * 32);
        const int cw = (t < 15) ? 32 : 20;
        const float* xrow = lds + (t & 1) * 2112 + lane * 33;
#pragma unroll
        for (int c = 0; c < 8; ++c) {
            const int col = w * 8 + c;
            if (col < cw) {                            // uniform branch
                const int d = d0q + t * 32 + col;      // wave-uniform
                int duv;                               // force VGPR -> vector loads
                asm("v_mov_b32 %0, %1" : "=v"(duv) : "s"(d));
                const float* w0r = W0p + duv * 24;
                const float* w1r = W1p + duv * 24;
                float wa[21], wb[21];
#pragma unroll
                for (int j = 0; j < 5; ++j) {
                    *reinterpret_cast<float4*>(&wa[4 * j]) =
                        *reinterpret_cast<const float4*>(w0r + 4 * j);
                    *reinterpret_cast<float4*>(&wb[4 * j]) =
                        *reinterpret_cast<const float4*>(w1r + 4 * j);
                }
                wa[20] = w0r[20];
                wb[20] = w1r[20];
                const float xv = xrow[col];
#pragma unroll
                for (int k = 0; k < K_; ++k) a0[k] = fmaf(xv, wa[k], a0[k]);
#pragma unroll
                for (int k = 0; k < K_; ++k) a1[k] = fmaf(xv, wb[k], a1[k]);
            }
        }
        if (t < 15) write_tile((t + 1) & 1);
        __syncthreads();
    }

    auto reduce_store = [&](const float* acc, float* dst) {
        __syncthreads();
#pragma unroll
        for (int k = 0; k < K_; ++k) lds[tid * 23 + k] = acc[k];
        __syncthreads();
        for (int o = tid; o < 64 * K_; o += 256) {
            int tt = o / K_, j = o - tt * K_;
            float s = lds[tt * 23 + j] + lds[(64 + tt) * 23 + j] +
                      lds[(128 + tt) * 23 + j] + lds[(192 + tt) * 23 + j];
            dst[(size_t)(r0 + tt) * K_ + j] = s;
        }
    };

    float* const qd[4] = {q0, q1, q2, q3};
    float* const md[4] = {mp0, mp1, mp2, mp3};
    reduce_store(a0, qd[h]);
    reduce_store(a1, md[h]);
}

// ---------------- K1.5: finalize w0, compute w1 (LDS-staged) ---------------
// w0 = q0+q1+q2+q3 ; M = mp0+mp1 (d<1000) ; P = mp2+mp3 (d>=1000)
// w1[row,k] = P[row,k] + sum_j w0[row,j] * M[row+j-10, k]
__global__ __launch_bounds__(256)
void k_finish(const float* __restrict__ q0, const float* __restrict__ q1,
              const float* __restrict__ q2, const float* __restrict__ q3,
              const float* __restrict__ mp0, const float* __restrict__ mp1,
              const float* __restrict__ mp2, const float* __restrict__ mp3,
              float* __restrict__ w0f, float* __restrict__ w1f) {
    __shared__ float w0s[64 * K_];
    __shared__ float Ms[84 * K_];
    const int tid = threadIdx.x;
    const int r0 = blockIdx.x * 64;

    for (int o = tid; o < 64 * K_; o += 256) {
        size_t g = (size_t)r0 * K_ + o;
        w0s[o] = q0[g] + q1[g] + q2[g] + q3[g];
    }
    for (int o = tid; o < 84 * K_; o += 256) {
        int i = o / K_, j = o - i * K_;
        int rr = r0 - P_ + i;
        float v = 0.f;
        if (rr >= 0 && rr < NT_) {
            size_t g = (size_t)rr * K_ + j;
            v = mp0[g] + mp1[g];
        }
        Ms[o] = v;
    }
    __syncthreads();

    for (int o = tid; o < 64 * K_; o += 256) {
        int row = o / K_, k = o - row * K_;
        size_t g = (size_t)(r0 + row) * K_ + k;
        float acc = mp2[g] + mp3[g];
        int t = (r0 + row) & (T_ - 1);
#pragma unroll
        for (int j = 0; j < K_; ++j) {
            int tt = t + j - P_;
            if (tt >= 0 && tt < T_)
                acc = fmaf(w0s[row * K_ + j], Ms[(row + j) * K_ + k], acc);
        }
        w1f[g] = acc;
        w0f[g] = w0s[o];
    }
}

// ---------------- K2/K3: shift-conv, sliding register window ---------------
// block = (grp, n, 64-t-chunk, 128-d-seg); 4 waves x 16 rows x 128 d (f2/lane).
// Per output row: 21-deep float2 window slides down LDS tile (1 b64 read),
// coefs via uniform-broadcast ds_read_b128 from 24-padded wc. One barrier.
__global__ __launch_bounds__(256)
void k_conv(const float* __restrict__ x, const float* __restrict__ w0f,
            const float* __restrict__ w1f, float* __restrict__ out) {
    __shared__ float xsl[84][128];     // 43 KB
    __shared__ float wc[64 * 24];      // 6 KB, padded rows
    const int b = blockIdx.x;
    const int dseg = b & 7;
    const int tch  = (b >> 3) & 15;
    const int nn   = (b >> 7) & 15;
    const int grp  = b >> 11;
    const float* __restrict__ coef = grp ? w1f : w0f;
    const int dbase = grp * 1000;
    const int t0 = tch * 64;
    const int tid = threadIdx.x;
    const float* xb = x + (size_t)nn * T_ * D_;

    {   // stage x halo tile [t0-10, t0+74) x 128 cols
        const int scol = tid & 31, srow0 = tid >> 5;
#pragma unroll
        for (int pass = 0; pass < 11; ++pass) {
            int rr = srow0 + pass * 8;
            if (rr < 84) {
                int u = t0 - P_ + rr;
                int dl = dseg * 128 + scol * 4;
                float4 v = make_float4(0.f, 0.f, 0.f, 0.f);
                if (u >= 0 && u < T_ && dl < 1000)
                    v = *reinterpret_cast<const float4*>(xb + (size_t)u * D_ + dbase + dl);
                *reinterpret_cast<float4*>(&xsl[rr][scol * 4]) = v;
            }
        }
    }
    for (int o = tid; o < 64 * 24; o += 256) {   // stage coefs (24-padded)
        int tl = o / 24, k = o - tl * 24;
        wc[o] = (k < K_) ? coef[((size_t)nn * T_ + t0 + tl) * K_ + k] : 0.f;
    }
    __syncthreads();

    const int wv = tid >> 6, lane = tid & 63;
    const int rw = wv * 16;                      // wave's first output row (local)
    const int dcol = dseg * 128 + lane * 2;
    const bool act = (dcol < 1000);

    float2 win[21];                              // rows rw..rw+20, static-indexed
#pragma unroll
    for (int s = 0; s < 21; ++s)
        win[s] = *reinterpret_cast<const float2*>(&xsl[rw + s][lane * 2]);

    float* obase = out + ((size_t)nn * T_ + t0 + rw) * D_ + dbase + dcol;

#pragma unroll
    for (int i = 0; i < 16; ++i) {
        float cfa[24];
        const float4* cf = reinterpret_cast<const float4*>(&wc[(rw + i) * 24]);
#pragma unroll
        for (int j = 0; j < 5; ++j)
            *reinterpret_cast<float4*>(&cfa[4 * j]) = cf[j];   // broadcast b128
        cfa[20] = wc[(rw + i) * 24 + 20];
        float2 acc = make_float2(0.f, 0.f);
#pragma unroll
        for (int k = 0; k < K_; ++k) {
            const float2 xv = win[(i + k) % 21];               // static index
            acc.x = fmaf(cfa[k], xv.x, acc.x);
            acc.y = fmaf(cfa[k], xv.y, acc.y);
        }
        if (act) *reinterpret_cast<float2*>(obase + (size_t)i * D_) = acc;
        if (i < 15)                                            // slide window
            win[i % 21] = *reinterpret_cast<const float2*>(&xsl[rw + i + 21][lane * 2]);
    }
}

extern "C" void kernel_launch(void* const* d_in, const int* in_sizes, int n_in,
                              void* d_out, int out_size, void* d_ws, size_t ws_size,
                              hipStream_t stream) {
    const float* x  = (const float*)d_in[0];
    const float* W0 = (const float*)d_in[1];
    const float* W1 = (const float*)d_in[2];
    float* out = (float*)d_out;
    float* ws  = (float*)d_ws;

    const size_t CW = 344064;               // 16384*21
    float* W0p = ws;                        // 48000
    float* W1p = ws + 48000;                // 48000
    float* q0  = ws + 96000 + 0 * CW;
    float* q1  = ws + 96000 + 1 * CW;
    float* q2  = ws + 96000 + 2 * CW;
    float* q3  = ws + 96000 + 3 * CW;
    float* mp0 = ws + 96000 + 4 * CW;
    float* mp1 = ws + 96000 + 5 * CW;
    float* mp2 = ws + 96000 + 6 * CW;
    float* mp3 = ws + 96000 + 7 * CW;
    float* w0f = ws + 96000 + 8 * CW;
    float* w1f = ws + 96000 + 9 * CW;       // total ~14.2 MB

    hipLaunchKernelGGL(k_padW, dim3(188), dim3(256), 0, stream, W0, W1, W0p, W1p);
    hipLaunchKernelGGL(k_coef, dim3(1024), dim3(256), 0, stream,
                       x, W0p, W1p, q0, q1, q2, q3, mp0, mp1, mp2, mp3);
    hipLaunchKernelGGL(k_finish, dim3(256), dim3(256), 0, stream,
                       q0, q1, q2, q3, mp0, mp1, mp2, mp3, w0f, w1f);
    hipLaunchKernelGGL(k_conv, dim3(4096), dim3(256), 0, stream, x, w0f, w1f, out);
}